// Round 9
// baseline (700.841 us; speedup 1.0000x reference)
//
#include <hip/hip_runtime.h>
#include <math.h>

typedef __attribute__((ext_vector_type(8))) short bf16x8;
typedef __attribute__((ext_vector_type(4))) float f32x4;

// round-to-nearest-even float -> bf16 (as short)
__device__ __forceinline__ short f2bf(float f) {
    unsigned u = __float_as_uint(f);
    unsigned r = (u + 0x7FFFu + ((u >> 16) & 1u)) >> 16;
    return (short)r;
}
__device__ __forceinline__ float bf2f(short s) {
    return __uint_as_float(((unsigned)(unsigned short)s) << 16);
}

// XOR swizzle of a byte offset within a row (spreads 16B slots across 8 bank-groups)
__device__ __forceinline__ int swz(int row, int kbyte) {
    return kbyte ^ ((row & 7) << 4);
}

// ---------- sort A: histogram of tgt ----------
__global__ __launch_bounds__(256) void hist_kernel(
    const int* __restrict__ eidx, int* __restrict__ cnt, int E)
{
    for (long e = (long)blockIdx.x * blockDim.x + threadIdx.x; e < E;
         e += (long)gridDim.x * blockDim.x)
        atomicAdd(&cnt[eidx[E + e]], 1);
}

// ---------- sort B1: per-block inclusive scan + block sums ----------
__global__ __launch_bounds__(256) void scanA_kernel(
    const int* __restrict__ cnt, int* __restrict__ tmp, int* __restrict__ bsum, int N)
{
    __shared__ int sa[256], sb_[256];
    int t = threadIdx.x;
    int i = blockIdx.x * 256 + t;
    int val = (i < N) ? cnt[i] : 0;
    sa[t] = val;
    __syncthreads();
    int* src = sa; int* dst = sb_;
    for (int off = 1; off < 256; off <<= 1) {
        int v2 = src[t];
        if (t >= off) v2 += src[t - off];
        dst[t] = v2;
        __syncthreads();
        int* tm = src; src = dst; dst = tm;
    }
    if (i < N) tmp[i] = src[t];
    if (t == 255) bsum[blockIdx.x] = src[255];
}

// ---------- sort B2: exclusive scan of block sums (1 small block) ----------
__global__ __launch_bounds__(256) void scanB_kernel(
    const int* __restrict__ bsum, int* __restrict__ boff, int NB)
{
    __shared__ int sa[256], sb_[256];
    int t = threadIdx.x;
    int val = (t < NB) ? bsum[t] : 0;
    sa[t] = val;
    __syncthreads();
    int* src = sa; int* dst = sb_;
    for (int off = 1; off < 256; off <<= 1) {
        int v2 = src[t];
        if (t >= off) v2 += src[t - off];
        dst[t] = v2;
        __syncthreads();
        int* tm = src; src = dst; dst = tm;
    }
    if (t < NB) boff[t] = src[t] - val;   // exclusive
}

// ---------- sort B3: cursor = global exclusive prefix ----------
__global__ __launch_bounds__(256) void scanC_kernel(
    const int* __restrict__ cnt, const int* __restrict__ tmp,
    const int* __restrict__ boff, int* __restrict__ cursor, int N)
{
    int i = blockIdx.x * 256 + threadIdx.x;
    if (i < N) cursor[i] = tmp[i] - cnt[i] + boff[blockIdx.x];
}

// ---------- sort C: scatter packed (edge,src,tgt) records in tgt-sorted order ----------
__global__ __launch_bounds__(256) void scatter_kernel(
    const int* __restrict__ eidx, int* __restrict__ cursor,
    int4* __restrict__ sortedq, int E)
{
    for (long e = (long)blockIdx.x * blockDim.x + threadIdx.x; e < E;
         e += (long)gridDim.x * blockDim.x) {
        int sr = eidx[e];
        int tg = eidx[E + e];
        int pos = atomicAdd(&cursor[tg], 1);
        sortedq[pos] = make_int4((int)e, sr, tg, 0);
    }
}

// ---------- K1: q|k|v = node @ [Wq|Wk|Wv] via MFMA -> bf16 ----------
__global__ __launch_bounds__(256) void qkv_kernel(
    const float* __restrict__ x,
    const float* __restrict__ Wq, const float* __restrict__ Wk, const float* __restrict__ Wv,
    short* __restrict__ qb, short* __restrict__ kb_, short* __restrict__ vb, int N)
{
    __shared__ short sWT[12288];   // 192 n-rows x 64 k, bf16, 128B rows, swizzled
    int t = threadIdx.x;
    for (int i = t; i < 4096; i += 256) {
        int k = i >> 6, n = i & 63;
        int kby = k * 2;
        int off = n * 128 + (swz(n, kby & ~15) | (kby & 15));
        *(short*)((char*)sWT + off) = f2bf(Wq[i]);
        *(short*)((char*)sWT + 8192 + off) = f2bf(Wk[i]);
        *(short*)((char*)sWT + 16384 + off) = f2bf(Wv[i]);
    }
    __syncthreads();

    int lane = t & 63, w = t >> 6;
    int tile = blockIdx.x;
    f32x4 acc[12];
    #pragma unroll
    for (int nt = 0; nt < 12; nt++) acc[nt] = (f32x4){0.f, 0.f, 0.f, 0.f};

    int gr = tile * 64 + w * 16 + (lane & 15);
    int grc = min(gr, N - 1);
    #pragma unroll
    for (int kk = 0; kk < 2; kk++) {
        const float* base = x + (size_t)grc * 64 + kk * 32 + (lane >> 4) * 8;
        float4 x0 = *(const float4*)(base);
        float4 x1 = *(const float4*)(base + 4);
        bf16x8 a;
        a[0] = f2bf(x0.x); a[1] = f2bf(x0.y); a[2] = f2bf(x0.z); a[3] = f2bf(x0.w);
        a[4] = f2bf(x1.x); a[5] = f2bf(x1.y); a[6] = f2bf(x1.z); a[7] = f2bf(x1.w);
        #pragma unroll
        for (int nt = 0; nt < 12; nt++) {
            int ng = nt * 16 + (lane & 15);
            int kby = kk * 64 + (lane >> 4) * 16;
            bf16x8 b = *(const bf16x8*)((const char*)sWT + ng * 128 + swz(ng, kby));
            acc[nt] = __builtin_amdgcn_mfma_f32_16x16x32_bf16(a, b, acc[nt], 0, 0, 0);
        }
    }
    #pragma unroll
    for (int nt = 0; nt < 12; nt++)
        #pragma unroll
        for (int r = 0; r < 4; r++) {
            int row = tile * 64 + w * 16 + (lane >> 4) * 4 + r;
            if (row < N) {
                int col = nt * 16 + (lane & 15);
                short vv = f2bf(acc[nt][r]);
                if (col < 64)       qb[(size_t)row * 64 + col] = vv;
                else if (col < 128) kb_[(size_t)row * 64 + col - 64] = vv;
                else                vb[(size_t)row * 64 + col - 128] = vv;
            }
        }
}

// ---- stage 64x64 weight (transposed, bf16, swizzled rows of 128B) ----
__device__ __forceinline__ void stage_w64T(const float* __restrict__ W, short* sWT, int t) {
    for (int i = t; i < 4096; i += 256) {
        int k = i >> 6, n = i & 63;
        short vv = f2bf(W[i]);
        int kby = k * 2;
        int off = n * 128 + (swz(n, kby & ~15) | (kby & 15));
        *(short*)((char*)sWT + off) = vv;
    }
}

// ---------- K2: fused edge pass, WAVE-INDEPENDENT (no in-loop barriers) ----------
// Each wave owns 16 consecutive sorted edges per tile iteration. ep lives in a
// per-wave LDS strip; indices distributed by shfl; waves free-run for latency hiding.
__global__ __launch_bounds__(256) void edge_kernel(
    const float* __restrict__ ef, const int4* __restrict__ sortedq,
    const short* __restrict__ qb, const short* __restrict__ kb_,
    const short* __restrict__ vb, const float* __restrict__ We,
    float* __restrict__ denom, float* __restrict__ agg, int E)
{
    __shared__ short sWeT[4096];
    __shared__ float ep_s[4][16][68];      // per-wave strip, 272B rows (16B aligned)
    int t = threadIdx.x;
    stage_w64T(We, sWeT, t);
    __syncthreads();                        // once: weights visible to all

    int lane = t & 63, w = t >> 6;
    int ntiles = E >> 6;
    for (int tile = blockIdx.x; tile < ntiles; tile += gridDim.x) {
        size_t base = (size_t)tile * 64 + w * 16;   // this wave's 16 sorted slots

        // lanes 0..15 load the wave's records; everyone else gets them via shfl
        int4 rec = make_int4(0, 0, 0, 0);
        if (lane < 16) rec = sortedq[base + lane];

        // --- phase A: ep = ef[rows] @ We via MFMA; rows = rec.x of (lane&15) ---
        {
            int erow = __shfl(rec.x, lane & 15);
            f32x4 acc[4];
            #pragma unroll
            for (int nt = 0; nt < 4; nt++) acc[nt] = (f32x4){0.f, 0.f, 0.f, 0.f};
            #pragma unroll
            for (int kk = 0; kk < 2; kk++) {
                const f32x4* bp = (const f32x4*)(ef + (size_t)erow * 64 + kk * 32 + (lane >> 4) * 8);
                f32x4 x0 = __builtin_nontemporal_load(bp);
                f32x4 x1 = __builtin_nontemporal_load(bp + 1);
                bf16x8 a;
                a[0] = f2bf(x0.x); a[1] = f2bf(x0.y); a[2] = f2bf(x0.z); a[3] = f2bf(x0.w);
                a[4] = f2bf(x1.x); a[5] = f2bf(x1.y); a[6] = f2bf(x1.z); a[7] = f2bf(x1.w);
                #pragma unroll
                for (int nt = 0; nt < 4; nt++) {
                    int n = nt * 16 + (lane & 15);
                    int kby = kk * 64 + (lane >> 4) * 16;
                    bf16x8 b = *(const bf16x8*)((const char*)sWeT + n * 128 + swz(n, kby));
                    acc[nt] = __builtin_amdgcn_mfma_f32_16x16x32_bf16(a, b, acc[nt], 0, 0, 0);
                }
            }
            #pragma unroll
            for (int nt = 0; nt < 4; nt++)
                #pragma unroll
                for (int r = 0; r < 4; r++)
                    ep_s[w][(lane >> 4) * 4 + r][nt * 16 + (lane & 15)] = acc[nt][r];
        }
        // same-wave LDS RAW: compiler inserts lgkmcnt wait; no barrier needed.

        // --- phase B: scores + exp. lane = e_loc*4 + h (e_loc = lane>>2, h = lane&3) ---
        float ex;
        {
            int e_loc = lane >> 2, h = lane & 3;
            int srcB = __shfl(rec.y, e_loc);
            int tgtB = __shfl(rec.z, e_loc);
            const bf16x8* qp = (const bf16x8*)(qb + (size_t)tgtB * 64 + h * 16);
            const bf16x8* kp = (const bf16x8*)(kb_ + (size_t)srcB * 64 + h * 16);
            bf16x8 q0 = qp[0], q1 = qp[1];
            bf16x8 k0 = kp[0], k1 = kp[1];
            const f32x4* eprow = (const f32x4*)&ep_s[w][e_loc][h * 16];
            f32x4 e0 = eprow[0], e1 = eprow[1], e2 = eprow[2], e3 = eprow[3];
            float s = 0.f;
            #pragma unroll
            for (int j = 0; j < 4; j++) s += bf2f(q0[j]) * (bf2f(k0[j]) + e0[j]);
            #pragma unroll
            for (int j = 0; j < 4; j++) s += bf2f(q0[4 + j]) * (bf2f(k0[4 + j]) + e1[j]);
            #pragma unroll
            for (int j = 0; j < 4; j++) s += bf2f(q1[j]) * (bf2f(k1[j]) + e2[j]);
            #pragma unroll
            for (int j = 0; j < 4; j++) s += bf2f(q1[4 + j]) * (bf2f(k1[4 + j]) + e3[j]);
            ex = __expf(s * 0.25f);
        }

        // --- phase C: run-compressed aggregation over the wave's 16 sorted edges ---
        {
            int h = lane >> 4;                       // head for this output dim
            int cur = __shfl(rec.z, 0);
            float acc = 0.f, den = 0.f;
            #pragma unroll
            for (int i = 0; i < 16; i++) {
                int tg = __shfl(rec.z, i);
                int si = __shfl(rec.y, i);
                if (tg != cur) {                     // wave-uniform branch
                    atomicAdd(&agg[(size_t)cur * 64 + lane], acc);
                    if ((lane & 15) == 0) atomicAdd(&denom[(size_t)cur * 4 + h], den);
                    acc = 0.f; den = 0.f; cur = tg;
                }
                float exi = __shfl(ex, i * 4 + h);   // ex for edge i, head h
                float vvv = bf2f(vb[(size_t)si * 64 + lane]);
                acc += exi * (vvv + ep_s[w][i][lane]);
                den += exi;
            }
            atomicAdd(&agg[(size_t)cur * 64 + lane], acc);
            if ((lane & 15) == 0) atomicAdd(&denom[(size_t)cur * 4 + h], den);
        }
        // WAR on ep_s across tiles is same-wave: program order + waitcnt suffices.
    }
}

// ---------- K3: new_nodes = x + (agg/denom) @ Wo via MFMA -> bf16 ----------
__global__ __launch_bounds__(256) void wo_kernel(
    const float* __restrict__ agg, const float* __restrict__ denom,
    const float* __restrict__ x,
    const float* __restrict__ Wo, short* __restrict__ nnb, int N)
{
    __shared__ short sWT[4096];
    int t = threadIdx.x;
    stage_w64T(Wo, sWT, t);
    __syncthreads();

    int lane = t & 63, w = t >> 6;
    int tile = blockIdx.x;
    f32x4 acc[4];
    #pragma unroll
    for (int nt = 0; nt < 4; nt++) acc[nt] = (f32x4){0.f, 0.f, 0.f, 0.f};

    int gr = tile * 64 + w * 16 + (lane & 15);
    int grc = min(gr, N - 1);
    #pragma unroll
    for (int kk = 0; kk < 2; kk++) {
        int fbase = kk * 32 + (lane >> 4) * 8;
        int h = fbase >> 4;                 // all 8 elems share one head
        float d = denom[(size_t)grc * 4 + h] + 1e-9f;
        const float* base = agg + (size_t)grc * 64 + fbase;
        float4 x0 = *(const float4*)(base);
        float4 x1 = *(const float4*)(base + 4);
        float inv = 1.f / d;
        bf16x8 a;
        a[0] = f2bf(x0.x * inv); a[1] = f2bf(x0.y * inv);
        a[2] = f2bf(x0.z * inv); a[3] = f2bf(x0.w * inv);
        a[4] = f2bf(x1.x * inv); a[5] = f2bf(x1.y * inv);
        a[6] = f2bf(x1.z * inv); a[7] = f2bf(x1.w * inv);
        #pragma unroll
        for (int nt = 0; nt < 4; nt++) {
            int n = nt * 16 + (lane & 15);
            int kby = kk * 64 + (lane >> 4) * 16;
            bf16x8 b = *(const bf16x8*)((const char*)sWT + n * 128 + swz(n, kby));
            acc[nt] = __builtin_amdgcn_mfma_f32_16x16x32_bf16(a, b, acc[nt], 0, 0, 0);
        }
    }
    #pragma unroll
    for (int nt = 0; nt < 4; nt++)
        #pragma unroll
        for (int r = 0; r < 4; r++) {
            int row = tile * 64 + w * 16 + (lane >> 4) * 4 + r;
            if (row < N) {
                int col = nt * 16 + (lane & 15);
                nnb[(size_t)row * 64 + col] = f2bf(x[(size_t)row * 64 + col] + acc[nt][r]);
            }
        }
}

// ---------- K4: classifier via MFMA, wave-independent (no in-loop barriers) ----------
__global__ __launch_bounds__(256, 4) void cls_kernel(
    const short* __restrict__ nnb, const float* __restrict__ ef,
    const int* __restrict__ eidx,
    const float* __restrict__ W1, const float* __restrict__ b1,
    const float* __restrict__ W2, const float* __restrict__ b2,
    float* __restrict__ out, int E)
{
    __shared__ short sWt1[64 * 192];        // [n][k] bf16, swizzled (384B rows)
    __shared__ float sW2[128];
    __shared__ float sb1[64];
    __shared__ float sb2[2];
    int t = threadIdx.x;
    for (int i = t; i < 192 * 64; i += 256) {
        int k = i >> 6, n = i & 63;
        short vv = f2bf(W1[i]);
        int kby = k * 2;
        int off = n * 384 + (swz(n, kby & ~15) | (kby & 15));
        *(short*)((char*)sWt1 + off) = vv;
    }
    if (t < 128) sW2[t] = W2[t];
    if (t < 64) sb1[t] = b1[t];
    if (t < 2) sb2[t] = b2[t];
    __syncthreads();                         // once: read-only weights

    int lane = t & 63, w = t >> 6;
    int ntiles = E >> 6;
    for (int tile = blockIdx.x; tile < ntiles; tile += gridDim.x) {
        size_t tile64 = (size_t)tile * 64;
        size_t e16 = tile64 + w * 16 + (lane & 15);  // this lane's edge row
        int srcn = eidx[e16];                         // 4-way redundant, L1-served
        int tgtn = eidx[(size_t)E + e16];

        f32x4 acc[4];
        #pragma unroll
        for (int nt = 0; nt < 4; nt++) acc[nt] = (f32x4){0.f, 0.f, 0.f, 0.f};

        #pragma unroll
        for (int kk = 0; kk < 6; kk++) {
            bf16x8 a;
            if (kk < 4) {
                int nd = (kk < 2) ? srcn : tgtn;
                a = *(const bf16x8*)(nnb + (size_t)nd * 64 + (kk & 1) * 32 + (lane >> 4) * 8);
            } else {
                const f32x4* p = (const f32x4*)(ef + e16 * 64
                                                + (kk - 4) * 32 + (lane >> 4) * 8);
                f32x4 x0 = __builtin_nontemporal_load(p);
                f32x4 x1 = __builtin_nontemporal_load(p + 1);
                a[0] = f2bf(x0.x); a[1] = f2bf(x0.y); a[2] = f2bf(x0.z); a[3] = f2bf(x0.w);
                a[4] = f2bf(x1.x); a[5] = f2bf(x1.y); a[6] = f2bf(x1.z); a[7] = f2bf(x1.w);
            }
            #pragma unroll
            for (int nt = 0; nt < 4; nt++) {
                int n = nt * 16 + (lane & 15);
                int kby = kk * 64 + (lane >> 4) * 16;
                bf16x8 b = *(const bf16x8*)((const char*)sWt1 + n * 384 + swz(n, kby));
                acc[nt] = __builtin_amdgcn_mfma_f32_16x16x32_bf16(a, b, acc[nt], 0, 0, 0);
            }
        }

        // bias + exact GELU + second layer [64,64]@[64,2] via in-register shfl reduce.
        #pragma unroll
        for (int r = 0; r < 4; r++) {
            float p0 = 0.f, p1 = 0.f;
            #pragma unroll
            for (int nt = 0; nt < 4; nt++) {
                int col = nt * 16 + (lane & 15);
                float h = acc[nt][r] + sb1[col];
                float g = 0.5f * h * (1.f + erff(h * 0.70710678118654752f));
                p0 += g * sW2[col * 2 + 0];
                p1 += g * sW2[col * 2 + 1];
            }
            #pragma unroll
            for (int o = 1; o < 16; o <<= 1) {
                p0 += __shfl_xor(p0, o, 64);
                p1 += __shfl_xor(p1, o, 64);
            }
            if ((lane & 15) == 0) {
                int row = w * 16 + (lane >> 4) * 4 + r;
                out[(tile64 + (size_t)row) * 2 + 0] = p0 + sb2[0];
                out[(tile64 + (size_t)row) * 2 + 1] = p1 + sb2[1];
            }
        }
    }
}

extern "C" void kernel_launch(void* const* d_in, const int* in_sizes, int n_in,
                              void* d_out, int out_size, void* d_ws, size_t ws_size,
                              hipStream_t stream)
{
    const float* node = (const float*)d_in[0];
    const float* ef   = (const float*)d_in[1];
    const int*   eidx = (const int*)d_in[2];
    const float* Wq   = (const float*)d_in[3];
    const float* Wk   = (const float*)d_in[4];
    const float* Wv   = (const float*)d_in[5];
    const float* We   = (const float*)d_in[6];
    const float* Wo   = (const float*)d_in[7];
    const float* W1   = (const float*)d_in[8];
    const float* b1   = (const float*)d_in[9];
    const float* W2   = (const float*)d_in[10];
    const float* b2   = (const float*)d_in[11];
    float* out = (float*)d_out;

    int N = in_sizes[0] / 64;
    int E = in_sizes[1] / 64;
    size_t N64 = (size_t)N * 64;
    int NB = (N + 255) / 256;

    // workspace layout (16B-aligned first)
    int4*  sortedq = (int4*)d_ws;                    // E
    short* qb   = (short*)(sortedq + E);             // N64
    short* kb_  = qb + N64;
    short* vb   = kb_ + N64;
    short* nnb  = vb + N64;
    float* agg  = (float*)(nnb + N64);               // N*64, zeroed
    float* denom = agg + N64;                        // N*4, zeroed
    int*   cnt   = (int*)(denom + (size_t)N * 4);    // N, zeroed
    int*   cursor = cnt + N;                         // N
    int*   tmp    = cursor + N;                      // N
    int*   bsum   = tmp + N;                         // 256
    int*   boff   = bsum + 256;                      // 256

    // zero agg + denom + cnt in one contiguous memset
    hipMemsetAsync(agg, 0, (N64 + (size_t)N * 4 + (size_t)N) * 4, stream);

    hist_kernel<<<2048, 256, 0, stream>>>(eidx, cnt, E);
    scanA_kernel<<<NB, 256, 0, stream>>>(cnt, tmp, bsum, N);
    scanB_kernel<<<1, 256, 0, stream>>>(bsum, boff, NB);
    scanC_kernel<<<NB, 256, 0, stream>>>(cnt, tmp, boff, cursor, N);
    scatter_kernel<<<2048, 256, 0, stream>>>(eidx, cursor, sortedq, E);
    qkv_kernel<<<(N + 63) / 64, 256, 0, stream>>>(node, Wq, Wk, Wv, qb, kb_, vb, N);
    edge_kernel<<<2048, 256, 0, stream>>>(ef, sortedq, qb, kb_, vb, We, denom, agg, E);
    wo_kernel<<<(N + 63) / 64, 256, 0, stream>>>(agg, denom, node, Wo, nnb, N);
    cls_kernel<<<2048, 256, 0, stream>>>(nnb, ef, eidx, W1, b1, W2, b2, out, E);
}